// Round 14
// baseline (136.154 us; speedup 1.0000x reference)
//
#include <hip/hip_runtime.h>

#define EPSV 1e-5f

typedef __attribute__((ext_vector_type(8))) short bf16x8;
typedef __attribute__((ext_vector_type(4))) float f32x4;

__device__ __forceinline__ unsigned short f2bf(float x) {
  unsigned u = __float_as_uint(x);
  unsigned r = (u + 0x7FFFu + ((u >> 16) & 1u)) >> 16;
  return (unsigned short)r;
}

__device__ __forceinline__ float block_reduce_sum(float v, float* lds) {
  #pragma unroll
  for (int off = 32; off > 0; off >>= 1) v += __shfl_down(v, off, 64);
  int lane = threadIdx.x & 63;
  int wid  = threadIdx.x >> 6;
  __syncthreads();
  if (lane == 0) lds[wid] = v;
  __syncthreads();
  float r = 0.f;
  if (threadIdx.x == 0) {
    int nw = blockDim.x >> 6;
    for (int i = 0; i < nw; ++i) r += lds[i];
  }
  return r;
}

// Stage x[b] (3x32x32) into zero-padded LDS [3][34][34].
__device__ __forceinline__ void stage_x(const float* __restrict__ x, float* xt, int b, int tid) {
  {
    float4* t4 = (float4*)xt;
    #pragma unroll
    for (int i = 0; i < 4; ++i) {
      int idx = i * 256 + tid;
      if (idx < 867) t4[idx] = make_float4(0.f, 0.f, 0.f, 0.f);
    }
  }
  __syncthreads();
  {
    const float4* x4 = (const float4*)(x + b * 3072);
    #pragma unroll
    for (int k = 0; k < 3; ++k) {
      int e4 = k * 256 + tid;
      float4 v = x4[e4];
      int w0 = e4 * 4;
      int ch = w0 >> 10;
      int pos = w0 & 1023;
      int r = pos >> 5, c = pos & 31;
      int base = ch * 1156 + (r + 1) * 34 + (c + 1);
      xt[base] = v.x; xt[base + 1] = v.y; xt[base + 2] = v.z; xt[base + 3] = v.w;
    }
  }
  __syncthreads();
}

// K1 v5: conv1 + stats partials; grid 1024, all 16 co per thread.
// Block 0 also builds the MFMA A-fragments of w2: wA[s][m][p][lane][8e].
__global__ __launch_bounds__(256) void k1_conv1_stats(
    const float* __restrict__ x, const float* __restrict__ w1, const float* __restrict__ b1,
    float* __restrict__ partials /* [16][2][1024] */,
    const float* __restrict__ w2, short* __restrict__ wA) {
  __shared__ float xt[3468];
  __shared__ float red[128];
  const int tid = threadIdx.x, b = blockIdx.x;

  if (b == 0) {  // one-time A-fragment build: all 18432 entries
    for (int i = tid; i < 18432; i += 256) {
      int e = i & 7, l = (i >> 3) & 63, p = (i >> 9) & 1, m = (i >> 10) & 1, s = i >> 11;
      int co = m * 16 + (l & 15);
      int ci = (l >> 4) * 8 + e;
      int ky = s / 3, kx = s - ky * 3;
      float wv = w2[((co * 32 + ci) * 3 + ky) * 3 + kx];
      unsigned short h = f2bf(wv);
      unsigned short val = p ? f2bf(wv - __uint_as_float((unsigned)h << 16)) : h;
      wA[i] = (short)val;
    }
  }

  stage_x(x, xt, b, tid);

  const int c = tid & 31, r0 = (tid >> 5) * 4;
  const int sbase = r0 * 34 + c;
  float xv[54];
  #pragma unroll
  for (int ci = 0; ci < 3; ++ci)
    #pragma unroll
    for (int dr = 0; dr < 6; ++dr)
      #pragma unroll
      for (int dx = 0; dx < 3; ++dx)
        xv[ci * 18 + dr * 3 + dx] = xt[ci * 1156 + sbase + dr * 34 + dx];

  const int lane = tid & 63, wid = tid >> 6;
  #pragma unroll
  for (int co = 0; co < 16; ++co) {
    float a0, a1, a2, a3;
    a0 = a1 = a2 = a3 = b1[co];
    #pragma unroll
    for (int ci = 0; ci < 3; ++ci)
      #pragma unroll
      for (int ky = 0; ky < 3; ++ky)
        #pragma unroll
        for (int kx = 0; kx < 3; ++kx) {
          float w = w1[co * 27 + ci * 9 + ky * 3 + kx];
          a0 = fmaf(xv[ci * 18 + (0 + ky) * 3 + kx], w, a0);
          a1 = fmaf(xv[ci * 18 + (1 + ky) * 3 + kx], w, a1);
          a2 = fmaf(xv[ci * 18 + (2 + ky) * 3 + kx], w, a2);
          a3 = fmaf(xv[ci * 18 + (3 + ky) * 3 + kx], w, a3);
        }
    float s = a0 + a1 + a2 + a3;
    float q = fmaf(a0, a0, fmaf(a1, a1, fmaf(a2, a2, a3 * a3)));
    #pragma unroll
    for (int o = 32; o > 0; o >>= 1) {
      s += __shfl_down(s, o, 64);
      q += __shfl_down(q, o, 64);
    }
    if (lane == 0) { red[wid * 32 + co * 2] = s; red[wid * 32 + co * 2 + 1] = q; }
  }
  __syncthreads();
  if (tid < 32) {
    int co = tid >> 1, sel = tid & 1;
    float r = red[co * 2 + sel] + red[32 + co * 2 + sel] +
              red[64 + co * 2 + sel] + red[96 + co * 2 + sel];
    partials[(co * 2 + sel) * 1024 + b] = r;
  }
}

// K2/K6: reduce partials -> scale/shift per channel.
__global__ __launch_bounds__(256) void k_bn_finalize(
    const float* __restrict__ partials, int nb, float invN,
    const float* __restrict__ gamma, const float* __restrict__ beta,
    float* __restrict__ stats, int C) {
  __shared__ float lds[4];
  int c = blockIdx.x;
  float s = 0.f, q = 0.f;
  for (int i = threadIdx.x; i < nb; i += blockDim.x) {
    s += partials[(c * 2 + 0) * nb + i];
    q += partials[(c * 2 + 1) * nb + i];
  }
  s = block_reduce_sum(s, lds);
  q = block_reduce_sum(q, lds);
  if (threadIdx.x == 0) {
    float mean = s * invN;
    float var  = q * invN - mean * mean;
    float scale = gamma[c] * rsqrtf(var + EPSV);
    stats[c]     = scale;
    stats[C + c] = beta[c] - mean * scale;
  }
}

// K3 v6: conv1 + BN + ReLU + basis_pool -> h1b bf16 hi/lo. Grid 1024.
// Thread = one cell (oh,ow); computes all 16 conv channels, packs the full
// 128 B cell [32 hi | 32 lo] and writes it contiguously (full-line writes).
__global__ __launch_bounds__(256) void k3_pool1(
    const float* __restrict__ x, const float* __restrict__ w1, const float* __restrict__ b1,
    const float* __restrict__ stats1, const float* __restrict__ pw, const float* __restrict__ pb,
    short* __restrict__ h1b) {
  __shared__ float xt[3468];
  const int tid = threadIdx.x, b = blockIdx.x;

  // Zero the 68 border cells (full 128 B each).
  for (int t = tid; t < 544; t += 256) {
    int i = t >> 3, chunk = t & 7;
    int r, cc;
    if (i < 18)      { r = 0;  cc = i; }
    else if (i < 36) { r = 17; cc = i - 18; }
    else { int j = i - 36; r = 1 + (j >> 1); cc = (j & 1) * 17; }
    int4 z = make_int4(0, 0, 0, 0);
    *(int4*)(h1b + ((size_t)(b * 324 + r * 18 + cc)) * 64 + chunk * 8) = z;
  }

  stage_x(x, xt, b, tid);

  const int ow = tid & 15, oh = tid >> 4;
  const int wbase = (2 * oh) * 34 + 2 * ow;
  float xv[48];
  #pragma unroll
  for (int ci = 0; ci < 3; ++ci)
    #pragma unroll
    for (int dr = 0; dr < 4; ++dr)
      #pragma unroll
      for (int dx = 0; dx < 4; ++dx)
        xv[ci * 16 + dr * 4 + dx] = xt[ci * 1156 + wbase + dr * 34 + dx];

  const float pw0 = pw[0] * 10.f, pw1 = pw[1] * 10.f;
  const float pb0 = pb[0] * 10.f, pb1 = pb[1] * 10.f;
  unsigned hiw[16], low[16];
  #pragma unroll
  for (int c = 0; c < 16; ++c) {
    const float scale = stats1[c], shift = stats1[16 + c];
    float v[4];
    #pragma unroll
    for (int p = 0; p < 4; ++p) {
      int dh = p >> 1, dw = p & 1;
      float a = b1[c];
      #pragma unroll
      for (int ci = 0; ci < 3; ++ci)
        #pragma unroll
        for (int ky = 0; ky < 3; ++ky)
          #pragma unroll
          for (int kx = 0; kx < 3; ++kx)
            a = fmaf(xv[ci * 16 + (dh + ky) * 4 + (dw + kx)], w1[(c * 3 + ci) * 9 + ky * 3 + kx], a);
      a = fmaf(a, scale, shift);
      v[p] = fmaxf(a, 0.f);
    }
    float o0, o1;
    #pragma unroll
    for (int k = 0; k < 2; ++k) {
      float cw = k ? pw1 : pw0;
      float cb = k ? pb1 : pb0;
      float s0 = fmaf(v[0], cw, cb), s1 = fmaf(v[1], cw, cb);
      float s2 = fmaf(v[2], cw, cb), s3 = fmaf(v[3], cw, cb);
      float m = fmaxf(fmaxf(s0, s1), fmaxf(s2, s3));
      float e0 = expf(s0 - m), e1 = expf(s1 - m), e2 = expf(s2 - m), e3 = expf(s3 - m);
      float den = e0 + e1 + e2 + e3;
      float outv = (v[0] * e0 + v[1] * e1 + v[2] * e2 + v[3] * e3) / den;
      if (k == 0) o0 = outv; else o1 = outv;
    }
    unsigned short h0 = f2bf(o0), h1 = f2bf(o1);
    float f0 = __uint_as_float((unsigned)h0 << 16);
    float f1 = __uint_as_float((unsigned)h1 << 16);
    unsigned short l0 = f2bf(o0 - f0), l1 = f2bf(o1 - f1);
    hiw[c] = (unsigned)h0 | ((unsigned)h1 << 16);
    low[c] = (unsigned)l0 | ((unsigned)l1 << 16);
  }

  short* cellp = h1b + ((size_t)(b * 324 + (oh + 1) * 18 + (ow + 1))) * 64;
  #pragma unroll
  for (int k = 0; k < 4; ++k) *(int4*)(cellp + k * 8)      = *(int4*)&hiw[k * 4];
  #pragma unroll
  for (int k = 0; k < 4; ++k) *(int4*)(cellp + 32 + k * 8) = *(int4*)&low[k * 4];
}

// K4 v12: conv2 via bf16 MFMA with hi/lo split. One block per image.
// LDS: [plane][324 cells][40 shorts]. Wave w: rows w*4..w*4+3, both co-tiles.
// Fused BN2 partial stats -> partials [32][2][4096], slot b*4+w.
__global__ __launch_bounds__(256) void k4_conv2(
    const short* __restrict__ h1b, const short* __restrict__ wA, const float* __restrict__ b2,
    float* __restrict__ y2, float* __restrict__ partials) {
  __shared__ __align__(16) short bh[25920];  // 2 planes x 324 x 40
  const int tid = threadIdx.x, b = blockIdx.x;

  for (int idx = tid; idx < 324; idx += 256) {
    const int4* gc = (const int4*)(h1b + (size_t)b * 20736) + idx * 8;
    int4 g0 = gc[0], g1 = gc[1], g2 = gc[2], g3 = gc[3];
    int4 g4 = gc[4], g5 = gc[5], g6 = gc[6], g7 = gc[7];
    int4* lp0 = (int4*)&bh[idx * 40];
    lp0[0] = g0; lp0[1] = g1; lp0[2] = g2; lp0[3] = g3;
    int4* lp1 = (int4*)&bh[12960 + idx * 40];
    lp1[0] = g4; lp1[1] = g5; lp1[2] = g6; lp1[3] = g7;
  }
  __syncthreads();

  const int l = tid & 63;
  const int w = tid >> 6;
  const int q = l >> 4;
  const int c = l & 15;
  const int rbase = w * 4;

  f32x4 acc[2][4];
  #pragma unroll
  for (int m = 0; m < 2; ++m) {
    f32x4 bj = *(const f32x4*)&b2[m * 16 + q * 4];
    #pragma unroll
    for (int r = 0; r < 4; ++r) acc[m][r] = bj;
  }

  const bf16x8* wAf = (const bf16x8*)wA;
  for (int ky = 0; ky < 3; ++ky) {
    for (int kx = 0; kx < 3; ++kx) {
      const int s = ky * 3 + kx;
      bf16x8 a0h = wAf[((s * 2 + 0) * 2 + 0) * 64 + l];
      bf16x8 a0l = wAf[((s * 2 + 0) * 2 + 1) * 64 + l];
      bf16x8 a1h = wAf[((s * 2 + 1) * 2 + 0) * 64 + l];
      bf16x8 a1l = wAf[((s * 2 + 1) * 2 + 1) * 64 + l];
      #pragma unroll
      for (int r = 0; r < 4; ++r) {
        const int pos = (rbase + r + ky) * 18 + (c + kx);
        bf16x8 bhv = *(const bf16x8*)&bh[pos * 40 + q * 8];
        bf16x8 blv = *(const bf16x8*)&bh[12960 + pos * 40 + q * 8];
        acc[0][r] = __builtin_amdgcn_mfma_f32_16x16x32_bf16(a0h, bhv, acc[0][r], 0, 0, 0);
        acc[0][r] = __builtin_amdgcn_mfma_f32_16x16x32_bf16(a0h, blv, acc[0][r], 0, 0, 0);
        acc[0][r] = __builtin_amdgcn_mfma_f32_16x16x32_bf16(a0l, bhv, acc[0][r], 0, 0, 0);
        acc[1][r] = __builtin_amdgcn_mfma_f32_16x16x32_bf16(a1h, bhv, acc[1][r], 0, 0, 0);
        acc[1][r] = __builtin_amdgcn_mfma_f32_16x16x32_bf16(a1h, blv, acc[1][r], 0, 0, 0);
        acc[1][r] = __builtin_amdgcn_mfma_f32_16x16x32_bf16(a1l, bhv, acc[1][r], 0, 0, 0);
      }
    }
  }

  {
    float* yb = y2 + b * 8192;
    #pragma unroll
    for (int m = 0; m < 2; ++m)
      #pragma unroll
      for (int r = 0; r < 4; ++r)
        #pragma unroll
        for (int j = 0; j < 4; ++j)
          yb[(m * 16 + q * 4 + j) * 256 + (rbase + r) * 16 + c] = acc[m][r][j];
  }

  const int slot = b * 4 + w;
  #pragma unroll
  for (int m = 0; m < 2; ++m) {
    #pragma unroll
    for (int j = 0; j < 4; ++j) {
      float a0 = acc[m][0][j], a1 = acc[m][1][j], a2 = acc[m][2][j], a3 = acc[m][3][j];
      float sv = a0 + a1 + a2 + a3;
      float qv = fmaf(a0, a0, fmaf(a1, a1, fmaf(a2, a2, a3 * a3)));
      #pragma unroll
      for (int o = 1; o <= 8; o <<= 1) {
        sv += __shfl_xor(sv, o, 64);
        qv += __shfl_xor(qv, o, 64);
      }
      if (c == 0) {
        int co = m * 16 + q * 4 + j;
        partials[(co * 2 + 0) * 4096 + slot] = sv;
        partials[(co * 2 + 1) * 4096 + slot] = qv;
      }
    }
  }
}

// K78: fused BN2-finalized pool2 + FC. One block per image.
__global__ __launch_bounds__(256) void k78_pool2_fc(
    const float* __restrict__ y2, const float* __restrict__ stats2,
    const float* __restrict__ pw, const float* __restrict__ pb,
    const float* __restrict__ fcw, const float* __restrict__ fcb,
    float* __restrict__ out) {
  __shared__ float h2s[4096];
  __shared__ float red[40];
  const int tid = threadIdx.x;
  const int b = blockIdx.x;

  {
    const int c = tid >> 3, oh = tid & 7;
    const float scale = stats2[c], shift = stats2[32 + c];
    const float pw0 = pw[0] * 10.f, pw1 = pw[1] * 10.f;
    const float pb0 = pb[0] * 10.f, pb1 = pb[1] * 10.f;
    const float* yb = y2 + (b * 32 + c) * 256 + (2 * oh) * 16;
    float rowa[16], rowb[16];
    #pragma unroll
    for (int k = 0; k < 4; ++k) {
      *(float4*)&rowa[k * 4] = ((const float4*)yb)[k];
      *(float4*)&rowb[k * 4] = ((const float4*)(yb + 16))[k];
    }
    #pragma unroll
    for (int ow = 0; ow < 8; ++ow) {
      float v0 = fmaxf(fmaf(rowa[2 * ow],     scale, shift), 0.f);
      float v1 = fmaxf(fmaf(rowa[2 * ow + 1], scale, shift), 0.f);
      float v2 = fmaxf(fmaf(rowb[2 * ow],     scale, shift), 0.f);
      float v3 = fmaxf(fmaf(rowb[2 * ow + 1], scale, shift), 0.f);
      #pragma unroll
      for (int k = 0; k < 2; ++k) {
        float cw = k ? pw1 : pw0;
        float cb = k ? pb1 : pb0;
        float s0 = fmaf(v0, cw, cb), s1 = fmaf(v1, cw, cb);
        float s2 = fmaf(v2, cw, cb), s3 = fmaf(v3, cw, cb);
        float m = fmaxf(fmaxf(s0, s1), fmaxf(s2, s3));
        float e0 = expf(s0 - m), e1 = expf(s1 - m), e2 = expf(s2 - m), e3 = expf(s3 - m);
        float den = e0 + e1 + e2 + e3;
        h2s[(c * 2 + k) * 64 + oh * 8 + ow] =
            (v0 * e0 + v1 * e1 + v2 * e2 + v3 * e3) / den;
      }
    }
  }
  __syncthreads();

  float acc[10];
  #pragma unroll
  for (int j = 0; j < 10; ++j) acc[j] = 0.f;
  #pragma unroll
  for (int k = 0; k < 16; ++k) {
    float hv = h2s[k * 256 + tid];
    #pragma unroll
    for (int j = 0; j < 10; ++j)
      acc[j] = fmaf(hv, fcw[j * 4096 + k * 256 + tid], acc[j]);
  }
  const int lane = tid & 63, wid = tid >> 6;
  #pragma unroll
  for (int j = 0; j < 10; ++j) {
    float v = acc[j];
    #pragma unroll
    for (int off = 32; off > 0; off >>= 1) v += __shfl_down(v, off, 64);
    if (lane == 0) red[wid * 10 + j] = v;
  }
  __syncthreads();
  if (tid < 10) {
    out[b * 10 + tid] = red[tid] + red[10 + tid] + red[20 + tid] + red[30 + tid] + fcb[tid];
  }
}

extern "C" void kernel_launch(void* const* d_in, const int* in_sizes, int n_in,
                              void* d_out, int out_size, void* d_ws, size_t ws_size,
                              hipStream_t stream) {
  (void)in_sizes; (void)n_in; (void)out_size; (void)ws_size;
  const float* x   = (const float*)d_in[0];
  const float* w1  = (const float*)d_in[1];
  const float* b1  = (const float*)d_in[2];
  const float* g1  = (const float*)d_in[3];
  const float* be1 = (const float*)d_in[4];
  const float* pw1 = (const float*)d_in[5];
  const float* pb1 = (const float*)d_in[6];
  const float* w2  = (const float*)d_in[7];
  const float* b2  = (const float*)d_in[8];
  const float* g2  = (const float*)d_in[9];
  const float* be2 = (const float*)d_in[10];
  const float* pw2 = (const float*)d_in[11];
  const float* pb2 = (const float*)d_in[12];
  const float* fcw = (const float*)d_in[13];
  const float* fcb = (const float*)d_in[14];
  float* out = (float*)d_out;

  char* ws = (char*)d_ws;
  short* h1b      = (short*)(ws);                          // 42.47 MB
  float* y2       = (float*)(ws + 44040192);               // 32 MiB
  float* partials = (float*)(ws + 44040192 + 33554432);    // 1 MiB
  short* wA       = (short*)(ws + 44040192 + 33554432 + 1048576);  // 36 KiB
  float* stats1   = (float*)(ws + 44040192 + 33554432 + 1048576 + 36864);
  float* stats2   = stats1 + 32;

  k1_conv1_stats<<<1024, 256, 0, stream>>>(x, w1, b1, partials, w2, wA);
  k_bn_finalize<<<16, 256, 0, stream>>>(partials, 1024, 1.f / 1048576.f, g1, be1, stats1, 16);
  k3_pool1<<<1024, 256, 0, stream>>>(x, w1, b1, stats1, pw1, pb1, h1b);
  k4_conv2<<<1024, 256, 0, stream>>>(h1b, wA, b2, y2, partials);
  k_bn_finalize<<<32, 256, 0, stream>>>(partials, 4096, 1.f / 262144.f, g2, be2, stats2, 32);
  k78_pool2_fc<<<1024, 256, 0, stream>>>(y2, stats2, pw2, pb2, fcw, fcb, out);
}

// Round 15
// 104.069 us; speedup vs baseline: 1.3083x; 1.3083x over previous
//
#include <hip/hip_runtime.h>

#define EPSV 1e-5f

typedef __attribute__((ext_vector_type(8))) short bf16x8;
typedef __attribute__((ext_vector_type(4))) float f32x4;

__device__ __forceinline__ unsigned short f2bf(float x) {
  unsigned u = __float_as_uint(x);
  unsigned r = (u + 0x7FFFu + ((u >> 16) & 1u)) >> 16;
  return (unsigned short)r;
}

__device__ __forceinline__ float block_reduce_sum(float v, float* lds) {
  #pragma unroll
  for (int off = 32; off > 0; off >>= 1) v += __shfl_down(v, off, 64);
  int lane = threadIdx.x & 63;
  int wid  = threadIdx.x >> 6;
  __syncthreads();
  if (lane == 0) lds[wid] = v;
  __syncthreads();
  float r = 0.f;
  if (threadIdx.x == 0) {
    int nw = blockDim.x >> 6;
    for (int i = 0; i < nw; ++i) r += lds[i];
  }
  return r;
}

// Stage x[b] (3x32x32) into zero-padded LDS region [3][34][34] floats.
__device__ __forceinline__ void stage_x(const float* __restrict__ x, float* xt, int b, int tid) {
  {
    float4* t4 = (float4*)xt;
    #pragma unroll
    for (int i = 0; i < 4; ++i) {
      int idx = i * 256 + tid;
      if (idx < 867) t4[idx] = make_float4(0.f, 0.f, 0.f, 0.f);
    }
  }
  __syncthreads();
  {
    const float4* x4 = (const float4*)(x + b * 3072);
    #pragma unroll
    for (int k = 0; k < 3; ++k) {
      int e4 = k * 256 + tid;
      float4 v = x4[e4];
      int w0 = e4 * 4;
      int ch = w0 >> 10;
      int pos = w0 & 1023;
      int r = pos >> 5, c = pos & 31;
      int base = ch * 1156 + (r + 1) * 34 + (c + 1);
      xt[base] = v.x; xt[base + 1] = v.y; xt[base + 2] = v.z; xt[base + 3] = v.w;
    }
  }
  __syncthreads();
}

// K1 (r13 shape): conv1 + stats partials; grid (1024, 2): 8 of 16 co per block.
// Block b==0 of each y builds half the MFMA A-fragments of w2.
__global__ __launch_bounds__(256) void k1_conv1_stats(
    const float* __restrict__ x, const float* __restrict__ w1, const float* __restrict__ b1,
    float* __restrict__ partials /* [16][2][1024] */,
    const float* __restrict__ w2, short* __restrict__ wA) {
  __shared__ float xt[3468];
  __shared__ float red[64];
  const int tid = threadIdx.x, b = blockIdx.x;
  const int co0 = blockIdx.y * 8;

  if (b == 0) {  // one-time A-fragment build: 18432 total, 9216 per y-block
    for (int i = tid + blockIdx.y * 9216; i < (blockIdx.y + 1) * 9216; i += 256) {
      int e = i & 7, l = (i >> 3) & 63, p = (i >> 9) & 1, m = (i >> 10) & 1, s = i >> 11;
      int co = m * 16 + (l & 15);
      int ci = (l >> 4) * 8 + e;
      int ky = s / 3, kx = s - ky * 3;
      float wv = w2[((co * 32 + ci) * 3 + ky) * 3 + kx];
      unsigned short h = f2bf(wv);
      unsigned short val = p ? f2bf(wv - __uint_as_float((unsigned)h << 16)) : h;
      wA[i] = (short)val;
    }
  }

  stage_x(x, xt, b, tid);

  const int c = tid & 31, r0 = (tid >> 5) * 4;
  const int sbase = r0 * 34 + c;
  float xv[54];
  #pragma unroll
  for (int ci = 0; ci < 3; ++ci)
    #pragma unroll
    for (int dr = 0; dr < 6; ++dr)
      #pragma unroll
      for (int dx = 0; dx < 3; ++dx)
        xv[ci * 18 + dr * 3 + dx] = xt[ci * 1156 + sbase + dr * 34 + dx];

  const int lane = tid & 63, wid = tid >> 6;
  #pragma unroll
  for (int cl = 0; cl < 8; ++cl) {
    const int co = co0 + cl;
    float a0, a1, a2, a3;
    a0 = a1 = a2 = a3 = b1[co];
    #pragma unroll
    for (int ci = 0; ci < 3; ++ci)
      #pragma unroll
      for (int ky = 0; ky < 3; ++ky)
        #pragma unroll
        for (int kx = 0; kx < 3; ++kx) {
          float w = w1[co * 27 + ci * 9 + ky * 3 + kx];
          a0 = fmaf(xv[ci * 18 + (0 + ky) * 3 + kx], w, a0);
          a1 = fmaf(xv[ci * 18 + (1 + ky) * 3 + kx], w, a1);
          a2 = fmaf(xv[ci * 18 + (2 + ky) * 3 + kx], w, a2);
          a3 = fmaf(xv[ci * 18 + (3 + ky) * 3 + kx], w, a3);
        }
    float s = a0 + a1 + a2 + a3;
    float q = fmaf(a0, a0, fmaf(a1, a1, fmaf(a2, a2, a3 * a3)));
    #pragma unroll
    for (int o = 32; o > 0; o >>= 1) {
      s += __shfl_down(s, o, 64);
      q += __shfl_down(q, o, 64);
    }
    if (lane == 0) { red[wid * 16 + cl * 2] = s; red[wid * 16 + cl * 2 + 1] = q; }
  }
  __syncthreads();
  if (tid < 16) {
    int cl = tid >> 1, sel = tid & 1;
    float r = red[cl * 2 + sel] + red[16 + cl * 2 + sel] +
              red[32 + cl * 2 + sel] + red[48 + cl * 2 + sel];
    partials[((co0 + cl) * 2 + sel) * 1024 + b] = r;
  }
}

// K2/K6: reduce partials -> scale/shift per channel.
__global__ __launch_bounds__(256) void k_bn_finalize(
    const float* __restrict__ partials, int nb, float invN,
    const float* __restrict__ gamma, const float* __restrict__ beta,
    float* __restrict__ stats, int C) {
  __shared__ float lds[4];
  int c = blockIdx.x;
  float s = 0.f, q = 0.f;
  for (int i = threadIdx.x; i < nb; i += blockDim.x) {
    s += partials[(c * 2 + 0) * nb + i];
    q += partials[(c * 2 + 1) * nb + i];
  }
  s = block_reduce_sum(s, lds);
  q = block_reduce_sum(q, lds);
  if (threadIdx.x == 0) {
    float mean = s * invN;
    float var  = q * invN - mean * mean;
    float scale = gamma[c] * rsqrtf(var + EPSV);
    stats[c]     = scale;
    stats[C + c] = beta[c] - mean * scale;
  }
}

// K34: FUSED conv1+BN1+ReLU+pool1 (phase A, LDS-resident) + conv2 MFMA (phase B).
// One block per image. LDS bh[25920] shorts doubles as xt float region in
// phase A0 (reads into regs before overwrite, syncthreads-fenced).
// Phase B: wave w: rows w*4..w*4+3, both 16-co tiles; hi/lo bf16 split MFMA.
// Fused BN2 partial stats -> partials [32][2][4096], slot b*4+w.
__global__ __launch_bounds__(256) void k34_pool1_conv2(
    const float* __restrict__ x, const float* __restrict__ w1, const float* __restrict__ b1,
    const float* __restrict__ stats1, const float* __restrict__ pw, const float* __restrict__ pb,
    const short* __restrict__ wA, const float* __restrict__ b2,
    float* __restrict__ y2, float* __restrict__ partials) {
  __shared__ __align__(16) short bh[25920];  // 51.84 KB: [2 planes][324 cells][40]
  const int tid = threadIdx.x, b = blockIdx.x;

  // Phase A0: stage x[b] into the first 13.9 KB of bh (as floats).
  float* xt = (float*)bh;
  stage_x(x, xt, b, tid);

  // Phase A1: pull this thread's 4x4x3 window into registers.
  const int ow = tid & 15, oh = tid >> 4;
  const int wbase = (2 * oh) * 34 + 2 * ow;
  float xv[48];
  #pragma unroll
  for (int ci = 0; ci < 3; ++ci)
    #pragma unroll
    for (int dr = 0; dr < 4; ++dr)
      #pragma unroll
      for (int dx = 0; dx < 4; ++dx)
        xv[ci * 16 + dr * 4 + dx] = xt[ci * 1156 + wbase + dr * 34 + dx];
  __syncthreads();  // all xt reads done; bh may now be overwritten

  // Phase A2: zero the 68 border cells on both planes (80 B = 5 int4 each).
  for (int t = tid; t < 680; t += 256) {
    int plane = t >= 340;
    int u = plane ? t - 340 : t;
    int i = u / 5, part = u - i * 5;
    int r, cc;
    if (i < 18)      { r = 0;  cc = i; }
    else if (i < 36) { r = 17; cc = i - 18; }
    else { int j = i - 36; r = 1 + (j >> 1); cc = (j & 1) * 17; }
    *(int4*)&bh[plane * 12960 + (r * 18 + cc) * 40 + part * 8] = make_int4(0, 0, 0, 0);
  }

  // Phase A3: conv1 + BN + ReLU + basis_pool for all 16 channels; pack hi/lo.
  {
    const float pw0 = pw[0] * 10.f, pw1 = pw[1] * 10.f;
    const float pb0 = pb[0] * 10.f, pb1 = pb[1] * 10.f;
    unsigned hiw[16], low[16];
    #pragma unroll
    for (int c = 0; c < 16; ++c) {
      const float scale = stats1[c], shift = stats1[16 + c];
      float v[4];
      #pragma unroll
      for (int p = 0; p < 4; ++p) {
        int dh = p >> 1, dw = p & 1;
        float a = b1[c];
        #pragma unroll
        for (int ci = 0; ci < 3; ++ci)
          #pragma unroll
          for (int ky = 0; ky < 3; ++ky)
            #pragma unroll
            for (int kx = 0; kx < 3; ++kx)
              a = fmaf(xv[ci * 16 + (dh + ky) * 4 + (dw + kx)], w1[(c * 3 + ci) * 9 + ky * 3 + kx], a);
        a = fmaf(a, scale, shift);
        v[p] = fmaxf(a, 0.f);
      }
      float o0, o1;
      #pragma unroll
      for (int k = 0; k < 2; ++k) {
        float cw = k ? pw1 : pw0;
        float cb = k ? pb1 : pb0;
        float s0 = fmaf(v[0], cw, cb), s1 = fmaf(v[1], cw, cb);
        float s2 = fmaf(v[2], cw, cb), s3 = fmaf(v[3], cw, cb);
        float m = fmaxf(fmaxf(s0, s1), fmaxf(s2, s3));
        float e0 = expf(s0 - m), e1 = expf(s1 - m), e2 = expf(s2 - m), e3 = expf(s3 - m);
        float den = e0 + e1 + e2 + e3;
        float outv = (v[0] * e0 + v[1] * e1 + v[2] * e2 + v[3] * e3) / den;
        if (k == 0) o0 = outv; else o1 = outv;
      }
      unsigned short h0 = f2bf(o0), h1 = f2bf(o1);
      float f0 = __uint_as_float((unsigned)h0 << 16);
      float f1 = __uint_as_float((unsigned)h1 << 16);
      unsigned short l0 = f2bf(o0 - f0), l1 = f2bf(o1 - f1);
      hiw[c] = (unsigned)h0 | ((unsigned)h1 << 16);
      low[c] = (unsigned)l0 | ((unsigned)l1 << 16);
    }
    const int cell = (oh + 1) * 18 + (ow + 1);
    #pragma unroll
    for (int k = 0; k < 4; ++k) *(int4*)&bh[cell * 40 + k * 8]         = *(int4*)&hiw[k * 4];
    #pragma unroll
    for (int k = 0; k < 4; ++k) *(int4*)&bh[12960 + cell * 40 + k * 8] = *(int4*)&low[k * 4];
  }
  __syncthreads();

  // Phase B: conv2 via bf16 MFMA (hi/lo split), read from LDS.
  const int l = tid & 63;
  const int w = tid >> 6;
  const int q = l >> 4;
  const int c = l & 15;
  const int rbase = w * 4;

  f32x4 acc[2][4];
  #pragma unroll
  for (int m = 0; m < 2; ++m) {
    f32x4 bj = *(const f32x4*)&b2[m * 16 + q * 4];
    #pragma unroll
    for (int r = 0; r < 4; ++r) acc[m][r] = bj;
  }

  const bf16x8* wAf = (const bf16x8*)wA;
  for (int ky = 0; ky < 3; ++ky) {
    for (int kx = 0; kx < 3; ++kx) {
      const int s = ky * 3 + kx;
      bf16x8 a0h = wAf[((s * 2 + 0) * 2 + 0) * 64 + l];
      bf16x8 a0l = wAf[((s * 2 + 0) * 2 + 1) * 64 + l];
      bf16x8 a1h = wAf[((s * 2 + 1) * 2 + 0) * 64 + l];
      bf16x8 a1l = wAf[((s * 2 + 1) * 2 + 1) * 64 + l];
      #pragma unroll
      for (int r = 0; r < 4; ++r) {
        const int pos = (rbase + r + ky) * 18 + (c + kx);
        bf16x8 bhv = *(const bf16x8*)&bh[pos * 40 + q * 8];
        bf16x8 blv = *(const bf16x8*)&bh[12960 + pos * 40 + q * 8];
        acc[0][r] = __builtin_amdgcn_mfma_f32_16x16x32_bf16(a0h, bhv, acc[0][r], 0, 0, 0);
        acc[0][r] = __builtin_amdgcn_mfma_f32_16x16x32_bf16(a0h, blv, acc[0][r], 0, 0, 0);
        acc[0][r] = __builtin_amdgcn_mfma_f32_16x16x32_bf16(a0l, bhv, acc[0][r], 0, 0, 0);
        acc[1][r] = __builtin_amdgcn_mfma_f32_16x16x32_bf16(a1h, bhv, acc[1][r], 0, 0, 0);
        acc[1][r] = __builtin_amdgcn_mfma_f32_16x16x32_bf16(a1h, blv, acc[1][r], 0, 0, 0);
        acc[1][r] = __builtin_amdgcn_mfma_f32_16x16x32_bf16(a1l, bhv, acc[1][r], 0, 0, 0);
      }
    }
  }

  // y2 write: D layout col=lane&15 (pos col), row=(lane>>4)*4+reg (co in tile).
  {
    float* yb = y2 + b * 8192;
    #pragma unroll
    for (int m = 0; m < 2; ++m)
      #pragma unroll
      for (int r = 0; r < 4; ++r)
        #pragma unroll
        for (int j = 0; j < 4; ++j)
          yb[(m * 16 + q * 4 + j) * 256 + (rbase + r) * 16 + c] = acc[m][r][j];
  }

  // Fused BN2 partial stats -> partials [32][2][4096], slot b*4+w.
  const int slot = b * 4 + w;
  #pragma unroll
  for (int m = 0; m < 2; ++m) {
    #pragma unroll
    for (int j = 0; j < 4; ++j) {
      float a0 = acc[m][0][j], a1 = acc[m][1][j], a2 = acc[m][2][j], a3 = acc[m][3][j];
      float sv = a0 + a1 + a2 + a3;
      float qv = fmaf(a0, a0, fmaf(a1, a1, fmaf(a2, a2, a3 * a3)));
      #pragma unroll
      for (int o = 1; o <= 8; o <<= 1) {
        sv += __shfl_xor(sv, o, 64);
        qv += __shfl_xor(qv, o, 64);
      }
      if (c == 0) {
        int co = m * 16 + q * 4 + j;
        partials[(co * 2 + 0) * 4096 + slot] = sv;
        partials[(co * 2 + 1) * 4096 + slot] = qv;
      }
    }
  }
}

// K78: fused BN2-finalized pool2 + FC. One block per image.
__global__ __launch_bounds__(256) void k78_pool2_fc(
    const float* __restrict__ y2, const float* __restrict__ stats2,
    const float* __restrict__ pw, const float* __restrict__ pb,
    const float* __restrict__ fcw, const float* __restrict__ fcb,
    float* __restrict__ out) {
  __shared__ float h2s[4096];
  __shared__ float red[40];
  const int tid = threadIdx.x;
  const int b = blockIdx.x;

  {
    const int c = tid >> 3, oh = tid & 7;
    const float scale = stats2[c], shift = stats2[32 + c];
    const float pw0 = pw[0] * 10.f, pw1 = pw[1] * 10.f;
    const float pb0 = pb[0] * 10.f, pb1 = pb[1] * 10.f;
    const float* yb = y2 + (b * 32 + c) * 256 + (2 * oh) * 16;
    float rowa[16], rowb[16];
    #pragma unroll
    for (int k = 0; k < 4; ++k) {
      *(float4*)&rowa[k * 4] = ((const float4*)yb)[k];
      *(float4*)&rowb[k * 4] = ((const float4*)(yb + 16))[k];
    }
    #pragma unroll
    for (int ow = 0; ow < 8; ++ow) {
      float v0 = fmaxf(fmaf(rowa[2 * ow],     scale, shift), 0.f);
      float v1 = fmaxf(fmaf(rowa[2 * ow + 1], scale, shift), 0.f);
      float v2 = fmaxf(fmaf(rowb[2 * ow],     scale, shift), 0.f);
      float v3 = fmaxf(fmaf(rowb[2 * ow + 1], scale, shift), 0.f);
      #pragma unroll
      for (int k = 0; k < 2; ++k) {
        float cw = k ? pw1 : pw0;
        float cb = k ? pb1 : pb0;
        float s0 = fmaf(v0, cw, cb), s1 = fmaf(v1, cw, cb);
        float s2 = fmaf(v2, cw, cb), s3 = fmaf(v3, cw, cb);
        float m = fmaxf(fmaxf(s0, s1), fmaxf(s2, s3));
        float e0 = expf(s0 - m), e1 = expf(s1 - m), e2 = expf(s2 - m), e3 = expf(s3 - m);
        float den = e0 + e1 + e2 + e3;
        h2s[(c * 2 + k) * 64 + oh * 8 + ow] =
            (v0 * e0 + v1 * e1 + v2 * e2 + v3 * e3) / den;
      }
    }
  }
  __syncthreads();

  float acc[10];
  #pragma unroll
  for (int j = 0; j < 10; ++j) acc[j] = 0.f;
  #pragma unroll
  for (int k = 0; k < 16; ++k) {
    float hv = h2s[k * 256 + tid];
    #pragma unroll
    for (int j = 0; j < 10; ++j)
      acc[j] = fmaf(hv, fcw[j * 4096 + k * 256 + tid], acc[j]);
  }
  const int lane = tid & 63, wid = tid >> 6;
  #pragma unroll
  for (int j = 0; j < 10; ++j) {
    float v = acc[j];
    #pragma unroll
    for (int off = 32; off > 0; off >>= 1) v += __shfl_down(v, off, 64);
    if (lane == 0) red[wid * 10 + j] = v;
  }
  __syncthreads();
  if (tid < 10) {
    out[b * 10 + tid] = red[tid] + red[10 + tid] + red[20 + tid] + red[30 + tid] + fcb[tid];
  }
}

extern "C" void kernel_launch(void* const* d_in, const int* in_sizes, int n_in,
                              void* d_out, int out_size, void* d_ws, size_t ws_size,
                              hipStream_t stream) {
  (void)in_sizes; (void)n_in; (void)out_size; (void)ws_size;
  const float* x   = (const float*)d_in[0];
  const float* w1  = (const float*)d_in[1];
  const float* b1  = (const float*)d_in[2];
  const float* g1  = (const float*)d_in[3];
  const float* be1 = (const float*)d_in[4];
  const float* pw1 = (const float*)d_in[5];
  const float* pb1 = (const float*)d_in[6];
  const float* w2  = (const float*)d_in[7];
  const float* b2  = (const float*)d_in[8];
  const float* g2  = (const float*)d_in[9];
  const float* be2 = (const float*)d_in[10];
  const float* pw2 = (const float*)d_in[11];
  const float* pb2 = (const float*)d_in[12];
  const float* fcw = (const float*)d_in[13];
  const float* fcb = (const float*)d_in[14];
  float* out = (float*)d_out;

  char* ws = (char*)d_ws;
  float* y2       = (float*)(ws);                          // 32 MiB
  float* partials = (float*)(ws + 33554432);               // 1 MiB ([32][2][4096])
  short* wA       = (short*)(ws + 33554432 + 1048576);     // 36 KiB
  float* stats1   = (float*)(ws + 33554432 + 1048576 + 36864);
  float* stats2   = stats1 + 32;

  dim3 g2d(1024, 2);
  k1_conv1_stats<<<g2d, 256, 0, stream>>>(x, w1, b1, partials, w2, wA);
  k_bn_finalize<<<16, 256, 0, stream>>>(partials, 1024, 1.f / 1048576.f, g1, be1, stats1, 16);
  k34_pool1_conv2<<<1024, 256, 0, stream>>>(x, w1, b1, stats1, pw1, pb1, wA, b2, y2, partials);
  k_bn_finalize<<<32, 256, 0, stream>>>(partials, 4096, 1.f / 262144.f, g2, be2, stats2, 32);
  k78_pool2_fc<<<1024, 256, 0, stream>>>(y2, stats2, pw2, pb2, fcw, fcb, out);
}